// Round 10
// baseline (635.434 us; speedup 1.0000x reference)
//
#include <hip/hip_runtime.h>

#define NN 16000   // nodes
#define NE 64000   // edges
#define HD 90      // hidden
#define NG 512     // graphs

typedef float f32x4 __attribute__((ext_vector_type(4)));
typedef short s16x8 __attribute__((ext_vector_type(8)));

// round-half-up f32 -> bf16
__device__ __forceinline__ unsigned short rhu1(float f) {
  return (unsigned short)((__builtin_bit_cast(unsigned int, f) + 0x8000u) >> 16);
}
// pack two f32 -> bf16x2 (lo in low half), RHU rounding
__device__ __forceinline__ unsigned int rhu_pack(float lo, float hi) {
  unsigned int ul = __builtin_bit_cast(unsigned int, lo) + 0x8000u;
  unsigned int uh = __builtin_bit_cast(unsigned int, hi) + 0x8000u;
  return __builtin_amdgcn_perm(uh, ul, 0x07060302u);
}
__device__ __forceinline__ float bfhi(unsigned int u) {
  return __builtin_bit_cast(float, u & 0xFFFF0000u);
}
__device__ __forceinline__ float bflo(unsigned int u) {
  return __builtin_bit_cast(float, u << 16);
}

// h0 = concat(x, pos) : [NN, 16]
__global__ void concat_kernel(const float* __restrict__ x, const float* __restrict__ pos,
                              float* __restrict__ h0) {
  int idx = blockIdx.x * 256 + threadIdx.x;
  if (idx >= NN * 16) return;
  int n = idx >> 4, c = idx & 15;
  h0[idx] = (c < 13) ? x[n * 13 + c] : pos[n * 3 + (c - 13)];
}

// he_bf[e][k] : [NE, 96] bf16. k<90: relu(edge MLP); k==90: 1.0 (bias row); k>90: 0
// R10: 4-wide — one thread per (e, quad of k). Same per-element fmaf chain
// + rhu1 (bit-identical); a[] row held in registers serves 4 outputs;
// ushort4 store. w1/b1 are L1-resident (2.9KB) so the k-stride-4 read is free.
// (R8 lesson: do NOT fuse this into msg_mfma — scratch spill.)
__global__ void edge_mlp_bf(const float* __restrict__ ea, const float* __restrict__ w1,
                            const float* __restrict__ b1, unsigned short* __restrict__ he) {
  int idx = blockIdx.x * 256 + threadIdx.x;
  if (idx >= NE * 24) return;
  int e = idx / 24, qd = idx - e * 24;
  const float* a = ea + e * 8;
  const float a0 = a[0], a1 = a[1], a2 = a[2], a3 = a[3];
  const float a4 = a[4], a5 = a[5], a6 = a[6], a7 = a[7];
  ushort4 v;
#pragma unroll
  for (int j = 0; j < 4; j++) {
    const int k = qd * 4 + j;
    unsigned short hv;
    if (k < 90) {
      float s = b1[k];
      s = fmaf(a0, w1[0 * HD + k], s);
      s = fmaf(a1, w1[1 * HD + k], s);
      s = fmaf(a2, w1[2 * HD + k], s);
      s = fmaf(a3, w1[3 * HD + k], s);
      s = fmaf(a4, w1[4 * HD + k], s);
      s = fmaf(a5, w1[5 * HD + k], s);
      s = fmaf(a6, w1[6 * HD + k], s);
      s = fmaf(a7, w1[7 * HD + k], s);
      hv = rhu1(fmaxf(s, 0.f));
    } else {
      hv = (k == 90) ? (unsigned short)0x3F80 : (unsigned short)0;
    }
    ((unsigned short*)&v)[j] = hv;
  }
  *(ushort4*)(he + (size_t)e * 96 + qd * 4) = v;
}

// W' prep in MFMA-B-fragment order: shorts laid out as
//   [i][tile t(NTT)][chunk c(3)][lane(64)][j(8)]
// value(i,t,c,lane,j): hk=c*32+(lane>>4)*8+j, o=t*16+(lane&15);
//   hk<90 -> w2[hk][i*OC+o]; hk==90 -> b2[i*OC+o]; else 0.   One block per (i,c).
template <int OC, int NTT>
__global__ void wprep_frag(const float* __restrict__ w2, const float* __restrict__ b2,
                           unsigned short* __restrict__ wout, int inc_oc) {
  const int i = blockIdx.x / 3, c = blockIdx.x - 3 * (blockIdx.x / 3);
  __shared__ float t_s[32 * 100];
  const int tid = threadIdx.x;
  for (int idx = tid; idx < 32 * 96; idx += 256) {
    int kk = idx / 96, o = idx - kk * 96;
    int hk = c * 32 + kk;
    float v = 0.f;
    if (o < OC) {
      if (hk < 90) v = w2[hk * inc_oc + i * OC + o];        // coalesced along o
      else if (hk == 90) v = b2[i * OC + o];
    }
    t_s[kk * 100 + o] = v;
  }
  __syncthreads();
  unsigned int* wo = (unsigned int*)(wout + (size_t)i * NTT * 3 * 512) + c * 256;
  for (int idx = tid; idx < NTT * 256; idx += 256) {
    int t = idx >> 8, r = idx & 255;
    int lane = r >> 2, u = r & 3;
    int kk = (lane >> 4) * 8 + 2 * u;
    int o = t * 16 + (lane & 15);
    wo[(size_t)t * 3 * 256 + lane * 4 + u] = rhu_pack(t_s[kk * 100 + o], t_s[(kk + 1) * 100 + o]);
  }
}

// Fused message GEMM + scatter, LDS-staged W' (R3) + MT=4 m-tiles/wave (R4)
// + distinct ping/pong LDS objects so AA lets stage-issue float past the
// ds_reads (R5; the only vmcnt(0) is the pre-barrier drain, covered by the
// MFMA phase). R6's counted-vmcnt ring REGRESSED 1.75x (broadcast W' stream
// x 500 blocks thrashes L2 + agg atomic lines). R8's in-kernel edge-MLP
// fusion REGRESSED 1.4x (scratch spill). R9's conv2 EPB=256 REGRESSED 8%:
// 84KB LDS -> 1 block/CU -> no second block to cover the per-iter barrier
// drain. RULE: keep >=2 blocks/CU for this drain-per-iter structure when
// the conv is barrier-overlap-bound (conv2); EPB=256 only pays where the
// trade-off differs (conv1: few iters; conv3: was 2-wave blocks).
template <int ILIM, int OC, int NTT, int NWG, int MT, int EPB, int BLK>
__global__ __launch_bounds__(BLK, 2)
void msg_mfma(const unsigned short* __restrict__ he,
              const float* __restrict__ nin,
              const int* __restrict__ src, const int* __restrict__ dst,
              const unsigned short* __restrict__ wp,
              float* __restrict__ agg) {
  constexpr int WMG = EPB / 32;          // 32-edge z-groups per block
  constexpr int TPE = BLK / EPB;
  constexpr int NWAVES = BLK / 64;       // = (EPB/(16*MT)) * NWG
  constexpr int NF = NTT * 3;            // 1KB fragments per i (whole W'[i])
  constexpr int MG = MT / 2;             // z-groups per wave
  __shared__ unsigned short zb[ILIM * WMG * 32];   // [i][grp][q][8] bf16, quad-permuted
  __shared__ unsigned short wbA[NF * 512];         // W' ping buffer (distinct object!)
  __shared__ unsigned short wbB[NF * 512];         // W' pong buffer (distinct object!)
  __shared__ int dst_s[EPB];
  const int tid = threadIdx.x;
  const int e0 = blockIdx.x * EPB;
  const int wid = tid >> 6, l = tid & 63, ln = tid & 15, q = (tid & 63) >> 4;
  const int wn = wid % NWG, wm = wid / NWG;
  const int eb = wm * MT * 16;
  const int wn3 = wn * 3;

  // stage W' slab (NF x 1KB fragments) -> the given LDS buffer, frags
  // distributed over waves. LDS dest is wave-uniform base (+lane*16);
  // global src is per-lane.
  const unsigned short* wl = wp + l * 8;
  auto stage = [&](const unsigned short* wb, unsigned short* lb) {
#pragma unroll
    for (int t = 0; t < (NF + NWAVES - 1) / NWAVES; t++) {
      const int s = wid + t * NWAVES;
      if (s < NF) {
        __builtin_amdgcn_global_load_lds(
            (const __attribute__((address_space(1))) unsigned int*)(wb + (size_t)s * 512),
            (__attribute__((address_space(3))) unsigned int*)(lb + s * 512),
            16, 0, 0);
      }
    }
  };

  // one i-step: z decode + 9 b128 W' reads from lb + 9*MT MFMA + acc FMA
  f32x4 acc[MT][3];
  s16x8 af[MT][3];
  auto compute = [&](int i, const unsigned short* lb) {
    f32x4 zv[MT];
#pragma unroll
    for (int g = 0; g < MG; g++) {
      const uint4 zu = *(const uint4*)&zb[(i * WMG + wm * MG + g) * 32 + q * 8];
      zv[2 * g][0] = bflo(zu.x); zv[2 * g][1] = bfhi(zu.x);
      zv[2 * g][2] = bflo(zu.y); zv[2 * g][3] = bfhi(zu.y);
      zv[2 * g + 1][0] = bflo(zu.z); zv[2 * g + 1][1] = bfhi(zu.z);
      zv[2 * g + 1][2] = bflo(zu.w); zv[2 * g + 1][3] = bfhi(zu.w);
    }
    uint4 ba[9];
#pragma unroll
    for (int ntl = 0; ntl < 3; ntl++)
#pragma unroll
      for (int c = 0; c < 3; c++)
        ba[ntl * 3 + c] = *(const uint4*)(lb + ((wn3 + ntl) * 3 + c) * 512 + l * 8);
#pragma unroll
    for (int ntl = 0; ntl < 3; ntl++) {
#pragma unroll
      for (int mt = 0; mt < MT; mt++) {
        f32x4 t = __builtin_amdgcn_mfma_f32_16x16x32_bf16(af[mt][0], __builtin_bit_cast(s16x8, ba[ntl * 3 + 0]), (f32x4)0.f, 0, 0, 0);
        t = __builtin_amdgcn_mfma_f32_16x16x32_bf16(af[mt][1], __builtin_bit_cast(s16x8, ba[ntl * 3 + 1]), t, 0, 0, 0);
        t = __builtin_amdgcn_mfma_f32_16x16x32_bf16(af[mt][2], __builtin_bit_cast(s16x8, ba[ntl * 3 + 2]), t, 0, 0, 0);
        acc[mt][ntl] += zv[mt] * t;
      }
    }
  };

  stage(wl, wbA);   // prefetch W'[0] while we stage z / load af

  if (tid < EPB) dst_s[tid] = dst[e0 + tid];

  // stage z (bf16) into quad-permuted layout:
  //   slot(e,i) = (i*WMG + (e>>5))*32 + ((e&15)>>2)*8 + ((e>>4)&1)*4 + (e&3)
  {
    const int e = tid % EPB, jj = tid / EPB;
    const int base = (e >> 5) * 32 + (((e & 15) >> 2) << 3) + (((e >> 4) & 1) << 2) + (e & 3);
    const float* zr = nin + (size_t)src[e0 + e] * ILIM;
    for (int p = jj; p < ILIM / 2; p += TPE) {
      const float2 v = *(const float2*)(zr + 2 * p);
      zb[(2 * p) * (WMG * 32) + base] = rhu1(v.x);
      zb[(2 * p + 1) * (WMG * 32) + base] = rhu1(v.y);
    }
  }

  // A-fragments: raw bf16 he, register-resident for the whole kernel
#pragma unroll
  for (int mt = 0; mt < MT; mt++) {
    const unsigned short* hr = he + (size_t)(e0 + eb + mt * 16 + ln) * 96 + q * 8;
#pragma unroll
    for (int c = 0; c < 3; c++) af[mt][c] = *(const s16x8*)(hr + c * 32);
  }

#pragma unroll
  for (int mt = 0; mt < MT; mt++)
#pragma unroll
    for (int nt = 0; nt < 3; nt++) acc[mt][nt] = (f32x4)0.f;

  __syncthreads();   // zb/dst_s ready AND wbA staged (vmcnt drained)

  const unsigned short* wnext = wl + (size_t)NF * 512;   // W'[1] base (per-lane)

#pragma clang loop unroll(disable)
  for (int i = 0; i < ILIM; i += 2) {
    // even half: stage i+1 -> wbB (distinct object: no false dep on wbA
    // reads), compute i from wbA, barrier (drains own stage loads).
    stage(wnext, wbB);
    wnext += (size_t)NF * 512;
    compute(i, wbA);
    __syncthreads();
    // odd half: stage i+2 -> wbA (if it exists), compute i+1 from wbB.
    if (i + 2 < ILIM) {
      stage(wnext, wbA);
      wnext += (size_t)NF * 512;
    }
    compute(i + 1, wbB);
    if (i + 2 < ILIM) __syncthreads();
  }

  // epilogue: D[row=q*4+r][col=ln] -> atomicAdd agg[dst]
#pragma unroll
  for (int mt = 0; mt < MT; mt++) {
#pragma unroll
    for (int ntl = 0; ntl < 3; ntl++) {
      int o = wn * 48 + ntl * 16 + ln;
      if (o < OC) {
#pragma unroll
        for (int r = 0; r < 4; r++) {
          int el = eb + mt * 16 + q * 4 + r;
          atomicAdd(agg + (size_t)dst_s[el] * OC + o, acc[mt][ntl][r]);
        }
      }
    }
  }
}

// out[n][o] = relu(agg[n][o] + sum_i nin[n][i]*root[i][o] + bias[o])   (fp32 exact)
// Also RE-ZEROES agg after reading (replaces the next conv's memset: same
// bytes, one fewer launch; same thread reads then writes its own idx — no
// hazard). This was the harmless half of R8 (the spill came from the MLP fusion).
template <int IN_C, int OC>
__global__ void node_kernel(const float* __restrict__ agg_r, float* __restrict__ agg,
                            const float* __restrict__ nin,
                            const float* __restrict__ root, const float* __restrict__ bias,
                            float* __restrict__ out) {
  int idx = blockIdx.x * 256 + threadIdx.x;
  if (idx >= NN * OC) return;
  int n = idx / OC, o = idx - n * OC;
  float acc = agg_r[idx] + bias[o];
  agg[idx] = 0.f;
  const float* inp = nin + (size_t)n * IN_C;
#pragma unroll 6
  for (int i = 0; i < IN_C; i++) acc = fmaf(inp[i], root[i * OC + o], acc);
  out[idx] = fmaxf(acc, 0.f);
}

// per-graph: pool (batch sorted -> binary search) + fc1 + out
__global__ void pool_mlp_kernel(const float* __restrict__ h3, const int* __restrict__ batch,
                                const float* __restrict__ fc1_w, const float* __restrict__ fc1_b,
                                const float* __restrict__ out_w, const float* __restrict__ out_b,
                                float* __restrict__ out) {
  const int b = blockIdx.x;
  const int tid = threadIdx.x;
  __shared__ float g[45];
  __shared__ float go[90];
  __shared__ int rng[2];
  if (tid < 2) {
    int target = b + tid;
    int lo = 0, hi = NN;
    while (lo < hi) { int mid = (lo + hi) >> 1; if (batch[mid] < target) lo = mid + 1; else hi = mid; }
    rng[tid] = lo;
  }
  __syncthreads();
  const int s = rng[0], e = rng[1];
  if (tid < 45) {
    float acc = 0.f;
    for (int n = s; n < e; n++) acc += h3[n * 45 + tid];
    g[tid] = acc;
  }
  __syncthreads();
  if (tid < 90) {
    float acc = fc1_b[tid];
#pragma unroll 5
    for (int i = 0; i < 45; i++) acc = fmaf(g[i], fc1_w[i * 90 + tid], acc);
    go[tid] = fmaxf(acc, 0.f) * out_w[tid];
  }
  __syncthreads();
  if (tid == 0) {
    float acc = out_b[0];
    for (int i = 0; i < 90; i++) acc += go[i];
    out[b] = acc;
  }
}

extern "C" void kernel_launch(void* const* d_in, const int* in_sizes, int n_in,
                              void* d_out, int out_size, void* d_ws, size_t ws_size,
                              hipStream_t stream) {
  const float* x       = (const float*)d_in[0];
  const float* pos     = (const float*)d_in[1];
  const float* ea      = (const float*)d_in[2];
  const int*   eidx    = (const int*)d_in[3];
  const int*   batch   = (const int*)d_in[4];
  const float* c1_w1   = (const float*)d_in[5];
  const float* c1_b1   = (const float*)d_in[6];
  const float* c1_w2   = (const float*)d_in[7];
  const float* c1_b2   = (const float*)d_in[8];
  const float* c1_root = (const float*)d_in[9];
  const float* c1_bias = (const float*)d_in[10];
  const float* c2_w1   = (const float*)d_in[11];
  const float* c2_b1   = (const float*)d_in[12];
  const float* c2_w2   = (const float*)d_in[13];
  const float* c2_b2   = (const float*)d_in[14];
  const float* c2_root = (const float*)d_in[15];
  const float* c2_bias = (const float*)d_in[16];
  const float* c3_w1   = (const float*)d_in[17];
  const float* c3_b1   = (const float*)d_in[18];
  const float* c3_w2   = (const float*)d_in[19];
  const float* c3_b2   = (const float*)d_in[20];
  const float* c3_root = (const float*)d_in[21];
  const float* c3_bias = (const float*)d_in[22];
  const float* fc1_w   = (const float*)d_in[23];
  const float* fc1_b   = (const float*)d_in[24];
  const float* out_w   = (const float*)d_in[25];
  const float* out_b   = (const float*)d_in[26];
  const int* src = eidx;
  const int* dst = eidx + NE;

  // workspace carve
  float* ws  = (float*)d_ws;
  float* h0  = ws;                       // NN*16
  float* h1  = h0 + NN * 16;             // NN*90
  float* h2  = h1 + NN * 90;             // NN*90
  float* h3  = h2 + NN * 90;             // NN*45
  float* agg = h3 + NN * 45;             // NN*90
  unsigned short* he_bf = (unsigned short*)(agg + NN * 90);   // NE*96
  unsigned short* wp1 = he_bf + (size_t)NE * 96;              // 16*6*3*512
  unsigned short* wp2 = wp1 + (size_t)16 * 6 * 3 * 512;       // 90*6*3*512
  unsigned short* wp3 = wp2 + (size_t)90 * 6 * 3 * 512;       // 90*3*3*512

  concat_kernel<<<(NN * 16) / 256, 256, 0, stream>>>(x, pos, h0);

  wprep_frag<90, 6><<<16 * 3, 256, 0, stream>>>(c1_w2, c1_b2, wp1, 16 * 90);
  wprep_frag<90, 6><<<90 * 3, 256, 0, stream>>>(c2_w2, c2_b2, wp2, 90 * 90);
  wprep_frag<45, 3><<<90 * 3, 256, 0, stream>>>(c3_w2, c3_b2, wp3, 90 * 45);

  // conv1: 16 -> 90   (256 edges/block, 8 waves: 4 wm(4 m-tiles) x 2 wn)
  hipMemsetAsync(agg, 0, (size_t)NN * 90 * sizeof(float), stream);
  edge_mlp_bf<<<(NE * 24 + 255) / 256, 256, 0, stream>>>(ea, c1_w1, c1_b1, he_bf);
  msg_mfma<16, 90, 6, 2, 4, 256, 512><<<NE / 256, 512, 0, stream>>>(he_bf, h0, src, dst, wp1, agg);
  node_kernel<16, 90><<<(NN * 90) / 256, 256, 0, stream>>>(agg, agg, h0, c1_root, c1_bias, h1);

  // conv2: 90 -> 90   (128 edges/block, 4 waves: 2 wm(4 m-tiles) x 2 wn) — proven R7 config
  edge_mlp_bf<<<(NE * 24 + 255) / 256, 256, 0, stream>>>(ea, c2_w1, c2_b1, he_bf);
  msg_mfma<90, 90, 6, 2, 4, 128, 256><<<NE / 128, 256, 0, stream>>>(he_bf, h1, src, dst, wp2, agg);
  node_kernel<90, 90><<<(NN * 90) / 256, 256, 0, stream>>>(agg, agg, h1, c2_root, c2_bias, h2);

  // conv3: 90 -> 45   (256 edges/block, 4 waves: 4 wm(4 m-tiles) x 1 wn)
  edge_mlp_bf<<<(NE * 24 + 255) / 256, 256, 0, stream>>>(ea, c3_w1, c3_b1, he_bf);
  msg_mfma<90, 45, 3, 1, 4, 256, 256><<<NE / 256, 256, 0, stream>>>(he_bf, h2, src, dst, wp3, agg);
  node_kernel<90, 45><<<(NN * 45 + 255) / 256, 256, 0, stream>>>(agg, agg, h2, c3_root, c3_bias, h3);

  pool_mlp_kernel<<<NG, 128, 0, stream>>>(h3, batch, fc1_w, fc1_b, out_w, out_b, (float*)d_out);
}

// Round 11
// 514.233 us; speedup vs baseline: 1.2357x; 1.2357x over previous
//
#include <hip/hip_runtime.h>

#define NN 16000   // nodes
#define NE 64000   // edges
#define HD 90      // hidden
#define NG 512     // graphs

typedef float f32x4 __attribute__((ext_vector_type(4)));
typedef short s16x8 __attribute__((ext_vector_type(8)));

// round-half-up f32 -> bf16
__device__ __forceinline__ unsigned short rhu1(float f) {
  return (unsigned short)((__builtin_bit_cast(unsigned int, f) + 0x8000u) >> 16);
}
// pack two f32 -> bf16x2 (lo in low half), RHU rounding
__device__ __forceinline__ unsigned int rhu_pack(float lo, float hi) {
  unsigned int ul = __builtin_bit_cast(unsigned int, lo) + 0x8000u;
  unsigned int uh = __builtin_bit_cast(unsigned int, hi) + 0x8000u;
  return __builtin_amdgcn_perm(uh, ul, 0x07060302u);
}
__device__ __forceinline__ float bfhi(unsigned int u) {
  return __builtin_bit_cast(float, u & 0xFFFF0000u);
}
__device__ __forceinline__ float bflo(unsigned int u) {
  return __builtin_bit_cast(float, u << 16);
}

// h0 = concat(x, pos) : [NN, 16]; ALSO zeroes agg[NN*90] (replaces the
// first memset launch — R11 launch-plumbing; grid = NN*90/256).
__global__ void concat_zero(const float* __restrict__ x, const float* __restrict__ pos,
                            float* __restrict__ h0, float* __restrict__ agg) {
  int idx = blockIdx.x * 256 + threadIdx.x;     // < NN*90
  agg[idx] = 0.f;
  if (idx < NN * 16) {
    int n = idx >> 4, c = idx & 15;
    h0[idx] = (c < 13) ? x[n * 13 + c] : pos[n * 3 + (c - 13)];
  }
}

// he_bf[e][k] : [NE, 96] bf16. k<90: relu(edge MLP); k==90: 1.0 (bias row); k>90: 0
// R7-proven 1-wide form. R8 lesson: do NOT fuse into msg_mfma (scratch
// spill). R10 lesson: the 4-wide rewrite regressed (address-taken local /
// bundled changes) — keep this exact kernel.
__global__ void edge_mlp_bf(const float* __restrict__ ea, const float* __restrict__ w1,
                            const float* __restrict__ b1, unsigned short* __restrict__ he) {
  int idx = blockIdx.x * 256 + threadIdx.x;
  if (idx >= NE * 96) return;
  int e = idx / 96, k = idx - e * 96;
  unsigned short v;
  if (k < 90) {
    const float* a = ea + e * 8;
    float acc = b1[k];
#pragma unroll
    for (int j = 0; j < 8; j++) acc = fmaf(a[j], w1[j * HD + k], acc);
    v = rhu1(fmaxf(acc, 0.f));
  } else {
    v = (k == 90) ? (unsigned short)0x3F80 : (unsigned short)0;  // bf16(1.0) / 0
  }
  he[idx] = v;
}

// W' prep in MFMA-B-fragment order (see R7 comment for the layout):
//   [i][tile t(NTT)][chunk c(3)][lane(64)][j(8)]
// R11: all three convs in ONE launch (blocks 0..47 conv1, 48..317 conv2,
// 318..587 conv3); body identical to the templated version, params runtime.
__global__ void wprep_all(const float* __restrict__ w2a, const float* __restrict__ b2a,
                          const float* __restrict__ w2b, const float* __restrict__ b2b,
                          const float* __restrict__ w2c, const float* __restrict__ b2c,
                          unsigned short* __restrict__ wo1, unsigned short* __restrict__ wo2,
                          unsigned short* __restrict__ wo3) {
  const int b = blockIdx.x;
  const float* w2; const float* b2; unsigned short* wout;
  int OC, NTT, inc, ib;
  if (b < 48)       { w2 = w2a; b2 = b2a; wout = wo1; OC = 90; NTT = 6; inc = 16 * 90; ib = b; }
  else if (b < 318) { w2 = w2b; b2 = b2b; wout = wo2; OC = 90; NTT = 6; inc = 90 * 90; ib = b - 48; }
  else              { w2 = w2c; b2 = b2c; wout = wo3; OC = 45; NTT = 3; inc = 90 * 45; ib = b - 318; }
  const int i = ib / 3, c = ib - 3 * i;
  __shared__ float t_s[32 * 100];
  const int tid = threadIdx.x;
  for (int idx = tid; idx < 32 * 96; idx += 256) {
    int kk = idx / 96, o = idx - kk * 96;
    int hk = c * 32 + kk;
    float v = 0.f;
    if (o < OC) {
      if (hk < 90) v = w2[hk * inc + i * OC + o];           // coalesced along o
      else if (hk == 90) v = b2[i * OC + o];
    }
    t_s[kk * 100 + o] = v;
  }
  __syncthreads();
  unsigned int* wo = (unsigned int*)(wout + (size_t)i * NTT * 3 * 512) + c * 256;
  for (int idx = tid; idx < NTT * 256; idx += 256) {
    int t = idx >> 8, r = idx & 255;
    int lane = r >> 2, u = r & 3;
    int kk = (lane >> 4) * 8 + 2 * u;
    int o = t * 16 + (lane & 15);
    wo[(size_t)t * 3 * 256 + lane * 4 + u] = rhu_pack(t_s[kk * 100 + o], t_s[(kk + 1) * 100 + o]);
  }
}

// Fused message GEMM + scatter, LDS-staged W' (R3) + MT=4 m-tiles/wave (R4)
// + distinct ping/pong LDS objects so AA lets stage-issue float past the
// ds_reads (R5; the only vmcnt(0) is the pre-barrier drain, covered by the
// MFMA phase). R6 counted-vmcnt ring: −1.75x (broadcast W' stream thrashes
// L2 + agg lines). R8 edge-MLP fusion: −1.4x (scratch spill). R9 conv2
// EPB=256: −8% (84KB LDS -> 1 block/CU -> nothing covers the per-iter
// barrier drain). RULE: keep >=2 blocks/CU for conv2; EPB=256 pays only
// where the trade-off differs (conv1: few iters; conv3: was 2-wave).
template <int ILIM, int OC, int NTT, int NWG, int MT, int EPB, int BLK>
__global__ __launch_bounds__(BLK, 2)
void msg_mfma(const unsigned short* __restrict__ he,
              const float* __restrict__ nin,
              const int* __restrict__ src, const int* __restrict__ dst,
              const unsigned short* __restrict__ wp,
              float* __restrict__ agg) {
  constexpr int WMG = EPB / 32;          // 32-edge z-groups per block
  constexpr int TPE = BLK / EPB;
  constexpr int NWAVES = BLK / 64;       // = (EPB/(16*MT)) * NWG
  constexpr int NF = NTT * 3;            // 1KB fragments per i (whole W'[i])
  constexpr int MG = MT / 2;             // z-groups per wave
  __shared__ unsigned short zb[ILIM * WMG * 32];   // [i][grp][q][8] bf16, quad-permuted
  __shared__ unsigned short wbA[NF * 512];         // W' ping buffer (distinct object!)
  __shared__ unsigned short wbB[NF * 512];         // W' pong buffer (distinct object!)
  __shared__ int dst_s[EPB];
  const int tid = threadIdx.x;
  const int e0 = blockIdx.x * EPB;
  const int wid = tid >> 6, l = tid & 63, ln = tid & 15, q = (tid & 63) >> 4;
  const int wn = wid % NWG, wm = wid / NWG;
  const int eb = wm * MT * 16;
  const int wn3 = wn * 3;

  // stage W' slab (NF x 1KB fragments) -> the given LDS buffer, frags
  // distributed over waves. LDS dest is wave-uniform base (+lane*16);
  // global src is per-lane.
  const unsigned short* wl = wp + l * 8;
  auto stage = [&](const unsigned short* wb, unsigned short* lb) {
#pragma unroll
    for (int t = 0; t < (NF + NWAVES - 1) / NWAVES; t++) {
      const int s = wid + t * NWAVES;
      if (s < NF) {
        __builtin_amdgcn_global_load_lds(
            (const __attribute__((address_space(1))) unsigned int*)(wb + (size_t)s * 512),
            (__attribute__((address_space(3))) unsigned int*)(lb + s * 512),
            16, 0, 0);
      }
    }
  };

  // one i-step: z decode + 9 b128 W' reads from lb + 9*MT MFMA + acc FMA
  f32x4 acc[MT][3];
  s16x8 af[MT][3];
  auto compute = [&](int i, const unsigned short* lb) {
    f32x4 zv[MT];
#pragma unroll
    for (int g = 0; g < MG; g++) {
      const uint4 zu = *(const uint4*)&zb[(i * WMG + wm * MG + g) * 32 + q * 8];
      zv[2 * g][0] = bflo(zu.x); zv[2 * g][1] = bfhi(zu.x);
      zv[2 * g][2] = bflo(zu.y); zv[2 * g][3] = bfhi(zu.y);
      zv[2 * g + 1][0] = bflo(zu.z); zv[2 * g + 1][1] = bfhi(zu.z);
      zv[2 * g + 1][2] = bflo(zu.w); zv[2 * g + 1][3] = bfhi(zu.w);
    }
    uint4 ba[9];
#pragma unroll
    for (int ntl = 0; ntl < 3; ntl++)
#pragma unroll
      for (int c = 0; c < 3; c++)
        ba[ntl * 3 + c] = *(const uint4*)(lb + ((wn3 + ntl) * 3 + c) * 512 + l * 8);
#pragma unroll
    for (int ntl = 0; ntl < 3; ntl++) {
#pragma unroll
      for (int mt = 0; mt < MT; mt++) {
        f32x4 t = __builtin_amdgcn_mfma_f32_16x16x32_bf16(af[mt][0], __builtin_bit_cast(s16x8, ba[ntl * 3 + 0]), (f32x4)0.f, 0, 0, 0);
        t = __builtin_amdgcn_mfma_f32_16x16x32_bf16(af[mt][1], __builtin_bit_cast(s16x8, ba[ntl * 3 + 1]), t, 0, 0, 0);
        t = __builtin_amdgcn_mfma_f32_16x16x32_bf16(af[mt][2], __builtin_bit_cast(s16x8, ba[ntl * 3 + 2]), t, 0, 0, 0);
        acc[mt][ntl] += zv[mt] * t;
      }
    }
  };

  stage(wl, wbA);   // prefetch W'[0] while we stage z / load af

  if (tid < EPB) dst_s[tid] = dst[e0 + tid];

  // stage z (bf16) into quad-permuted layout:
  //   slot(e,i) = (i*WMG + (e>>5))*32 + ((e&15)>>2)*8 + ((e>>4)&1)*4 + (e&3)
  {
    const int e = tid % EPB, jj = tid / EPB;
    const int base = (e >> 5) * 32 + (((e & 15) >> 2) << 3) + (((e >> 4) & 1) << 2) + (e & 3);
    const float* zr = nin + (size_t)src[e0 + e] * ILIM;
    for (int p = jj; p < ILIM / 2; p += TPE) {
      const float2 v = *(const float2*)(zr + 2 * p);
      zb[(2 * p) * (WMG * 32) + base] = rhu1(v.x);
      zb[(2 * p + 1) * (WMG * 32) + base] = rhu1(v.y);
    }
  }

  // A-fragments: raw bf16 he, register-resident for the whole kernel
#pragma unroll
  for (int mt = 0; mt < MT; mt++) {
    const unsigned short* hr = he + (size_t)(e0 + eb + mt * 16 + ln) * 96 + q * 8;
#pragma unroll
    for (int c = 0; c < 3; c++) af[mt][c] = *(const s16x8*)(hr + c * 32);
  }

#pragma unroll
  for (int mt = 0; mt < MT; mt++)
#pragma unroll
    for (int nt = 0; nt < 3; nt++) acc[mt][nt] = (f32x4)0.f;

  __syncthreads();   // zb/dst_s ready AND wbA staged (vmcnt drained)

  const unsigned short* wnext = wl + (size_t)NF * 512;   // W'[1] base (per-lane)

#pragma clang loop unroll(disable)
  for (int i = 0; i < ILIM; i += 2) {
    // even half: stage i+1 -> wbB (distinct object: no false dep on wbA
    // reads), compute i from wbA, barrier (drains own stage loads).
    stage(wnext, wbB);
    wnext += (size_t)NF * 512;
    compute(i, wbA);
    __syncthreads();
    // odd half: stage i+2 -> wbA (if it exists), compute i+1 from wbB.
    if (i + 2 < ILIM) {
      stage(wnext, wbA);
      wnext += (size_t)NF * 512;
    }
    compute(i + 1, wbB);
    if (i + 2 < ILIM) __syncthreads();
  }

  // epilogue: D[row=q*4+r][col=ln] -> atomicAdd agg[dst]
#pragma unroll
  for (int mt = 0; mt < MT; mt++) {
#pragma unroll
    for (int ntl = 0; ntl < 3; ntl++) {
      int o = wn * 48 + ntl * 16 + ln;
      if (o < OC) {
#pragma unroll
        for (int r = 0; r < 4; r++) {
          int el = eb + mt * 16 + q * 4 + r;
          atomicAdd(agg + (size_t)dst_s[el] * OC + o, acc[mt][ntl][r]);
        }
      }
    }
  }
}

// out[n][o] = relu(agg[n][o] + sum_i nin[n][i]*root[i][o] + bias[o])   (fp32 exact)
// Also RE-ZEROES agg[idx] after reading it — through the SAME pointer
// (no aliased-restrict pair, unlike R10's buggy form): load-before-store
// on the same address through one pointer is order-guaranteed. Replaces
// the next conv's memset launch; bytes identical.
template <int IN_C, int OC>
__global__ void node_kernel(float* __restrict__ agg, const float* __restrict__ nin,
                            const float* __restrict__ root, const float* __restrict__ bias,
                            float* __restrict__ out) {
  int idx = blockIdx.x * 256 + threadIdx.x;
  if (idx >= NN * OC) return;
  int n = idx / OC, o = idx - n * OC;
  float acc = agg[idx] + bias[o];
  agg[idx] = 0.f;
  const float* inp = nin + (size_t)n * IN_C;
#pragma unroll 6
  for (int i = 0; i < IN_C; i++) acc = fmaf(inp[i], root[i * OC + o], acc);
  out[idx] = fmaxf(acc, 0.f);
}

// per-graph: pool (batch sorted -> binary search) + fc1 + out
__global__ void pool_mlp_kernel(const float* __restrict__ h3, const int* __restrict__ batch,
                                const float* __restrict__ fc1_w, const float* __restrict__ fc1_b,
                                const float* __restrict__ out_w, const float* __restrict__ out_b,
                                float* __restrict__ out) {
  const int b = blockIdx.x;
  const int tid = threadIdx.x;
  __shared__ float g[45];
  __shared__ float go[90];
  __shared__ int rng[2];
  if (tid < 2) {
    int target = b + tid;
    int lo = 0, hi = NN;
    while (lo < hi) { int mid = (lo + hi) >> 1; if (batch[mid] < target) lo = mid + 1; else hi = mid; }
    rng[tid] = lo;
  }
  __syncthreads();
  const int s = rng[0], e = rng[1];
  if (tid < 45) {
    float acc = 0.f;
    for (int n = s; n < e; n++) acc += h3[n * 45 + tid];
    g[tid] = acc;
  }
  __syncthreads();
  if (tid < 90) {
    float acc = fc1_b[tid];
#pragma unroll 5
    for (int i = 0; i < 45; i++) acc = fmaf(g[i], fc1_w[i * 90 + tid], acc);
    go[tid] = fmaxf(acc, 0.f) * out_w[tid];
  }
  __syncthreads();
  if (tid == 0) {
    float acc = out_b[0];
    for (int i = 0; i < 90; i++) acc += go[i];
    out[b] = acc;
  }
}

extern "C" void kernel_launch(void* const* d_in, const int* in_sizes, int n_in,
                              void* d_out, int out_size, void* d_ws, size_t ws_size,
                              hipStream_t stream) {
  const float* x       = (const float*)d_in[0];
  const float* pos     = (const float*)d_in[1];
  const float* ea      = (const float*)d_in[2];
  const int*   eidx    = (const int*)d_in[3];
  const int*   batch   = (const int*)d_in[4];
  const float* c1_w1   = (const float*)d_in[5];
  const float* c1_b1   = (const float*)d_in[6];
  const float* c1_w2   = (const float*)d_in[7];
  const float* c1_b2   = (const float*)d_in[8];
  const float* c1_root = (const float*)d_in[9];
  const float* c1_bias = (const float*)d_in[10];
  const float* c2_w1   = (const float*)d_in[11];
  const float* c2_b1   = (const float*)d_in[12];
  const float* c2_w2   = (const float*)d_in[13];
  const float* c2_b2   = (const float*)d_in[14];
  const float* c2_root = (const float*)d_in[15];
  const float* c2_bias = (const float*)d_in[16];
  const float* c3_w1   = (const float*)d_in[17];
  const float* c3_b1   = (const float*)d_in[18];
  const float* c3_w2   = (const float*)d_in[19];
  const float* c3_b2   = (const float*)d_in[20];
  const float* c3_root = (const float*)d_in[21];
  const float* c3_bias = (const float*)d_in[22];
  const float* fc1_w   = (const float*)d_in[23];
  const float* fc1_b   = (const float*)d_in[24];
  const float* out_w   = (const float*)d_in[25];
  const float* out_b   = (const float*)d_in[26];
  const int* src = eidx;
  const int* dst = eidx + NE;

  // workspace carve
  float* ws  = (float*)d_ws;
  float* h0  = ws;                       // NN*16
  float* h1  = h0 + NN * 16;             // NN*90
  float* h2  = h1 + NN * 90;             // NN*90
  float* h3  = h2 + NN * 90;             // NN*45
  float* agg = h3 + NN * 45;             // NN*90
  unsigned short* he_bf = (unsigned short*)(agg + NN * 90);   // NE*96
  unsigned short* wp1 = he_bf + (size_t)NE * 96;              // 16*6*3*512
  unsigned short* wp2 = wp1 + (size_t)16 * 6 * 3 * 512;       // 90*6*3*512
  unsigned short* wp3 = wp2 + (size_t)90 * 6 * 3 * 512;       // 90*3*3*512

  // concat + agg-zero (1 launch), all W' prep (1 launch)
  concat_zero<<<(NN * 90) / 256, 256, 0, stream>>>(x, pos, h0, agg);
  wprep_all<<<16 * 3 + 90 * 3 + 90 * 3, 256, 0, stream>>>(
      c1_w2, c1_b2, c2_w2, c2_b2, c3_w2, c3_b2, wp1, wp2, wp3);

  // conv1: 16 -> 90   (256 edges/block, 8 waves: 4 wm(4 m-tiles) x 2 wn)
  edge_mlp_bf<<<(NE * 96) / 256, 256, 0, stream>>>(ea, c1_w1, c1_b1, he_bf);
  msg_mfma<16, 90, 6, 2, 4, 256, 512><<<NE / 256, 512, 0, stream>>>(he_bf, h0, src, dst, wp1, agg);
  node_kernel<16, 90><<<(NN * 90) / 256, 256, 0, stream>>>(agg, h0, c1_root, c1_bias, h1);

  // conv2: 90 -> 90   (128 edges/block, 4 waves: 2 wm(4 m-tiles) x 2 wn) — proven R7 config
  edge_mlp_bf<<<(NE * 96) / 256, 256, 0, stream>>>(ea, c2_w1, c2_b1, he_bf);
  msg_mfma<90, 90, 6, 2, 4, 128, 256><<<NE / 128, 256, 0, stream>>>(he_bf, h1, src, dst, wp2, agg);
  node_kernel<90, 90><<<(NN * 90) / 256, 256, 0, stream>>>(agg, h1, c2_root, c2_bias, h2);

  // conv3: 90 -> 45   (256 edges/block, 4 waves: 4 wm(4 m-tiles) x 1 wn)
  edge_mlp_bf<<<(NE * 96) / 256, 256, 0, stream>>>(ea, c3_w1, c3_b1, he_bf);
  msg_mfma<90, 45, 3, 1, 4, 256, 256><<<NE / 256, 256, 0, stream>>>(he_bf, h2, src, dst, wp3, agg);
  node_kernel<90, 45><<<(NN * 45 + 255) / 256, 256, 0, stream>>>(agg, h2, c3_root, c3_bias, h3);

  pool_mlp_kernel<<<NG, 128, 0, stream>>>(h3, batch, fc1_w, fc1_b, out_w, out_b, (float*)d_out);
}

// Round 12
// 495.074 us; speedup vs baseline: 1.2835x; 1.0387x over previous
//
#include <hip/hip_runtime.h>

#define NN 16000   // nodes
#define NE 64000   // edges
#define HD 90      // hidden
#define NG 512     // graphs

typedef float f32x4 __attribute__((ext_vector_type(4)));
typedef short s16x8 __attribute__((ext_vector_type(8)));

// round-half-up f32 -> bf16
__device__ __forceinline__ unsigned short rhu1(float f) {
  return (unsigned short)((__builtin_bit_cast(unsigned int, f) + 0x8000u) >> 16);
}
// pack two f32 -> bf16x2 (lo in low half), RHU rounding
__device__ __forceinline__ unsigned int rhu_pack(float lo, float hi) {
  unsigned int ul = __builtin_bit_cast(unsigned int, lo) + 0x8000u;
  unsigned int uh = __builtin_bit_cast(unsigned int, hi) + 0x8000u;
  return __builtin_amdgcn_perm(uh, ul, 0x07060302u);
}
__device__ __forceinline__ float bfhi(unsigned int u) {
  return __builtin_bit_cast(float, u & 0xFFFF0000u);
}
__device__ __forceinline__ float bflo(unsigned int u) {
  return __builtin_bit_cast(float, u << 16);
}

// shared edge-MLP body (R7-proven 1-wide form; bit-identical everywhere).
// R8 lesson: do NOT fuse into msg_mfma (scratch spill). R10 lesson: the
// 4-wide rewrite regressed — keep this exact form.
__device__ __forceinline__ void edge_mlp_one(int idx, const float* __restrict__ ea,
                                             const float* __restrict__ w1,
                                             const float* __restrict__ b1,
                                             unsigned short* __restrict__ he) {
  int e = idx / 96, k = idx - e * 96;
  unsigned short v;
  if (k < 90) {
    const float* a = ea + e * 8;
    float acc = b1[k];
#pragma unroll
    for (int j = 0; j < 8; j++) acc = fmaf(a[j], w1[j * HD + k], acc);
    v = rhu1(fmaxf(acc, 0.f));
  } else {
    v = (k == 90) ? (unsigned short)0x3F80 : (unsigned short)0;  // bf16(1.0) / 0
  }
  he[idx] = v;
}

// R12 mega-prep (1 launch, block-range dispatch; all parts independent):
//   blocks [0,5625):        h0 = concat(x,pos) + agg zero
//   blocks [5625,6213):     W' prep for all three convs (R11 wprep_all body)
//   blocks [6213,30213):    edge MLP for conv1 -> he
#define NB_CONCAT 5625      // NN*90/256
#define NB_WPREP  588       // 48 + 270 + 270
#define NB_EDGE   24000     // NE*96/256
__global__ void prep_kernel(const float* __restrict__ x, const float* __restrict__ pos,
                            float* __restrict__ h0, float* __restrict__ agg,
                            const float* __restrict__ w2a, const float* __restrict__ b2a,
                            const float* __restrict__ w2b, const float* __restrict__ b2b,
                            const float* __restrict__ w2c, const float* __restrict__ b2c,
                            unsigned short* __restrict__ wo1, unsigned short* __restrict__ wo2,
                            unsigned short* __restrict__ wo3,
                            const float* __restrict__ ea, const float* __restrict__ w1,
                            const float* __restrict__ b1, unsigned short* __restrict__ he) {
  const int b = blockIdx.x;
  const int tid = threadIdx.x;
  __shared__ float t_s[32 * 100];
  if (b < NB_CONCAT) {
    int idx = b * 256 + tid;                    // < NN*90
    agg[idx] = 0.f;
    if (idx < NN * 16) {
      int n = idx >> 4, c = idx & 15;
      h0[idx] = (c < 13) ? x[n * 13 + c] : pos[n * 3 + (c - 13)];
    }
    return;
  }
  if (b >= NB_CONCAT + NB_WPREP) {
    edge_mlp_one((b - NB_CONCAT - NB_WPREP) * 256 + tid, ea, w1, b1, he);
    return;
  }
  // --- wprep (R11 wprep_all body) ---
  const int wb = b - NB_CONCAT;
  const float* w2; const float* b2; unsigned short* wout;
  int OC, NTT, inc, ib;
  if (wb < 48)       { w2 = w2a; b2 = b2a; wout = wo1; OC = 90; NTT = 6; inc = 16 * 90; ib = wb; }
  else if (wb < 318) { w2 = w2b; b2 = b2b; wout = wo2; OC = 90; NTT = 6; inc = 90 * 90; ib = wb - 48; }
  else               { w2 = w2c; b2 = b2c; wout = wo3; OC = 45; NTT = 3; inc = 90 * 45; ib = wb - 318; }
  const int i = ib / 3, c = ib - 3 * i;
  for (int idx = tid; idx < 32 * 96; idx += 256) {
    int kk = idx / 96, o = idx - kk * 96;
    int hk = c * 32 + kk;
    float v = 0.f;
    if (o < OC) {
      if (hk < 90) v = w2[hk * inc + i * OC + o];           // coalesced along o
      else if (hk == 90) v = b2[i * OC + o];
    }
    t_s[kk * 100 + o] = v;
  }
  __syncthreads();
  unsigned int* wo = (unsigned int*)(wout + (size_t)i * NTT * 3 * 512) + c * 256;
  for (int idx = tid; idx < NTT * 256; idx += 256) {
    int t = idx >> 8, r = idx & 255;
    int lane = r >> 2, u = r & 3;
    int kk = (lane >> 4) * 8 + 2 * u;
    int o = t * 16 + (lane & 15);
    wo[(size_t)t * 3 * 256 + lane * 4 + u] = rhu_pack(t_s[kk * 100 + o], t_s[(kk + 1) * 100 + o]);
  }
}

// Fused message GEMM + scatter, LDS-staged W' (R3) + MT=4 m-tiles/wave (R4)
// + distinct ping/pong LDS objects so AA lets stage-issue float past the
// ds_reads (R5; the only vmcnt(0) is the pre-barrier drain, covered by the
// MFMA phase). R6 counted-vmcnt ring: −1.75x (broadcast W' stream thrashes
// L2 + agg lines). R8 edge-MLP fusion: −1.4x (scratch spill). R9 conv2
// EPB=256: −8% (84KB LDS -> 1 block/CU -> nothing covers the per-iter
// barrier drain). RULE: keep >=2 blocks/CU for conv2; EPB=256 pays only
// where the trade-off differs (conv1: few iters; conv3: was 2-wave).
// R11 note: 32x32x16 MFMA variant derived on paper — trades 1400->1163cyc
// MFMA for 960->1730cyc LDS per CU-iter at our wave/VGPR budget; net loss.
template <int ILIM, int OC, int NTT, int NWG, int MT, int EPB, int BLK>
__global__ __launch_bounds__(BLK, 2)
void msg_mfma(const unsigned short* __restrict__ he,
              const float* __restrict__ nin,
              const int* __restrict__ src, const int* __restrict__ dst,
              const unsigned short* __restrict__ wp,
              float* __restrict__ agg) {
  constexpr int WMG = EPB / 32;          // 32-edge z-groups per block
  constexpr int TPE = BLK / EPB;
  constexpr int NWAVES = BLK / 64;       // = (EPB/(16*MT)) * NWG
  constexpr int NF = NTT * 3;            // 1KB fragments per i (whole W'[i])
  constexpr int MG = MT / 2;             // z-groups per wave
  __shared__ unsigned short zb[ILIM * WMG * 32];   // [i][grp][q][8] bf16, quad-permuted
  __shared__ unsigned short wbA[NF * 512];         // W' ping buffer (distinct object!)
  __shared__ unsigned short wbB[NF * 512];         // W' pong buffer (distinct object!)
  __shared__ int dst_s[EPB];
  const int tid = threadIdx.x;
  const int e0 = blockIdx.x * EPB;
  const int wid = tid >> 6, l = tid & 63, ln = tid & 15, q = (tid & 63) >> 4;
  const int wn = wid % NWG, wm = wid / NWG;
  const int eb = wm * MT * 16;
  const int wn3 = wn * 3;

  // stage W' slab (NF x 1KB fragments) -> the given LDS buffer, frags
  // distributed over waves. LDS dest is wave-uniform base (+lane*16);
  // global src is per-lane.
  const unsigned short* wl = wp + l * 8;
  auto stage = [&](const unsigned short* wb, unsigned short* lb) {
#pragma unroll
    for (int t = 0; t < (NF + NWAVES - 1) / NWAVES; t++) {
      const int s = wid + t * NWAVES;
      if (s < NF) {
        __builtin_amdgcn_global_load_lds(
            (const __attribute__((address_space(1))) unsigned int*)(wb + (size_t)s * 512),
            (__attribute__((address_space(3))) unsigned int*)(lb + s * 512),
            16, 0, 0);
      }
    }
  };

  // one i-step: z decode + 9 b128 W' reads from lb + 9*MT MFMA + acc FMA
  f32x4 acc[MT][3];
  s16x8 af[MT][3];
  auto compute = [&](int i, const unsigned short* lb) {
    f32x4 zv[MT];
#pragma unroll
    for (int g = 0; g < MG; g++) {
      const uint4 zu = *(const uint4*)&zb[(i * WMG + wm * MG + g) * 32 + q * 8];
      zv[2 * g][0] = bflo(zu.x); zv[2 * g][1] = bfhi(zu.x);
      zv[2 * g][2] = bflo(zu.y); zv[2 * g][3] = bfhi(zu.y);
      zv[2 * g + 1][0] = bflo(zu.z); zv[2 * g + 1][1] = bfhi(zu.z);
      zv[2 * g + 1][2] = bflo(zu.w); zv[2 * g + 1][3] = bfhi(zu.w);
    }
    uint4 ba[9];
#pragma unroll
    for (int ntl = 0; ntl < 3; ntl++)
#pragma unroll
      for (int c = 0; c < 3; c++)
        ba[ntl * 3 + c] = *(const uint4*)(lb + ((wn3 + ntl) * 3 + c) * 512 + l * 8);
#pragma unroll
    for (int ntl = 0; ntl < 3; ntl++) {
#pragma unroll
      for (int mt = 0; mt < MT; mt++) {
        f32x4 t = __builtin_amdgcn_mfma_f32_16x16x32_bf16(af[mt][0], __builtin_bit_cast(s16x8, ba[ntl * 3 + 0]), (f32x4)0.f, 0, 0, 0);
        t = __builtin_amdgcn_mfma_f32_16x16x32_bf16(af[mt][1], __builtin_bit_cast(s16x8, ba[ntl * 3 + 1]), t, 0, 0, 0);
        t = __builtin_amdgcn_mfma_f32_16x16x32_bf16(af[mt][2], __builtin_bit_cast(s16x8, ba[ntl * 3 + 2]), t, 0, 0, 0);
        acc[mt][ntl] += zv[mt] * t;
      }
    }
  };

  stage(wl, wbA);   // prefetch W'[0] while we stage z / load af

  if (tid < EPB) dst_s[tid] = dst[e0 + tid];

  // stage z (bf16) into quad-permuted layout:
  //   slot(e,i) = (i*WMG + (e>>5))*32 + ((e&15)>>2)*8 + ((e>>4)&1)*4 + (e&3)
  {
    const int e = tid % EPB, jj = tid / EPB;
    const int base = (e >> 5) * 32 + (((e & 15) >> 2) << 3) + (((e >> 4) & 1) << 2) + (e & 3);
    const float* zr = nin + (size_t)src[e0 + e] * ILIM;
    for (int p = jj; p < ILIM / 2; p += TPE) {
      const float2 v = *(const float2*)(zr + 2 * p);
      zb[(2 * p) * (WMG * 32) + base] = rhu1(v.x);
      zb[(2 * p + 1) * (WMG * 32) + base] = rhu1(v.y);
    }
  }

  // A-fragments: raw bf16 he, register-resident for the whole kernel
#pragma unroll
  for (int mt = 0; mt < MT; mt++) {
    const unsigned short* hr = he + (size_t)(e0 + eb + mt * 16 + ln) * 96 + q * 8;
#pragma unroll
    for (int c = 0; c < 3; c++) af[mt][c] = *(const s16x8*)(hr + c * 32);
  }

#pragma unroll
  for (int mt = 0; mt < MT; mt++)
#pragma unroll
    for (int nt = 0; nt < 3; nt++) acc[mt][nt] = (f32x4)0.f;

  __syncthreads();   // zb/dst_s ready AND wbA staged (vmcnt drained)

  const unsigned short* wnext = wl + (size_t)NF * 512;   // W'[1] base (per-lane)

#pragma clang loop unroll(disable)
  for (int i = 0; i < ILIM; i += 2) {
    // even half: stage i+1 -> wbB (distinct object: no false dep on wbA
    // reads), compute i from wbA, barrier (drains own stage loads).
    stage(wnext, wbB);
    wnext += (size_t)NF * 512;
    compute(i, wbA);
    __syncthreads();
    // odd half: stage i+2 -> wbA (if it exists), compute i+1 from wbB.
    if (i + 2 < ILIM) {
      stage(wnext, wbA);
      wnext += (size_t)NF * 512;
    }
    compute(i + 1, wbB);
    if (i + 2 < ILIM) __syncthreads();
  }

  // epilogue: D[row=q*4+r][col=ln] -> atomicAdd agg[dst]
#pragma unroll
  for (int mt = 0; mt < MT; mt++) {
#pragma unroll
    for (int ntl = 0; ntl < 3; ntl++) {
      int o = wn * 48 + ntl * 16 + ln;
      if (o < OC) {
#pragma unroll
        for (int r = 0; r < 4; r++) {
          int el = eb + mt * 16 + q * 4 + r;
          atomicAdd(agg + (size_t)dst_s[el] * OC + o, acc[mt][ntl][r]);
        }
      }
    }
  }
}

// node body: out[n][o] = relu(agg[n][o] + sum_i nin[n][i]*root[i][o] + bias[o])
// (fp32 exact). Also RE-ZEROES agg[idx] after reading, through the SAME
// pointer (load-before-store, order-guaranteed) — replaces memset launches.
template <int IN_C, int OC>
__device__ __forceinline__ void node_one(int idx, float* __restrict__ agg,
                                         const float* __restrict__ nin,
                                         const float* __restrict__ root,
                                         const float* __restrict__ bias,
                                         float* __restrict__ out) {
  int n = idx / OC, o = idx - n * OC;
  float acc = agg[idx] + bias[o];
  agg[idx] = 0.f;
  const float* inp = nin + (size_t)n * IN_C;
#pragma unroll 6
  for (int i = 0; i < IN_C; i++) acc = fmaf(inp[i], root[i * OC + o], acc);
  out[idx] = fmaxf(acc, 0.f);
}

// R12: node(conv k) + edge-MLP(conv k+1) merged — independent work on
// disjoint buffers (edge depends only on ea; runs after msg k consumed the
// previous he). Grid = NE*96/256 = 24000 blocks; node active in the first
// NN*OC/256 blocks' range.
template <int IN_C, int OC>
__global__ void node_edge(float* __restrict__ agg, const float* __restrict__ nin,
                          const float* __restrict__ root, const float* __restrict__ bias,
                          float* __restrict__ out,
                          const float* __restrict__ ea, const float* __restrict__ w1,
                          const float* __restrict__ b1, unsigned short* __restrict__ he) {
  int idx = blockIdx.x * 256 + threadIdx.x;    // < NE*96 exactly
  edge_mlp_one(idx, ea, w1, b1, he);
  if (idx < NN * OC) node_one<IN_C, OC>(idx, agg, nin, root, bias, out);
}

// plain node (conv3 — no following edge MLP)
template <int IN_C, int OC>
__global__ void node_kernel(float* __restrict__ agg, const float* __restrict__ nin,
                            const float* __restrict__ root, const float* __restrict__ bias,
                            float* __restrict__ out) {
  int idx = blockIdx.x * 256 + threadIdx.x;
  if (idx >= NN * OC) return;
  node_one<IN_C, OC>(idx, agg, nin, root, bias, out);
}

// per-graph: pool (batch sorted -> binary search) + fc1 + out
__global__ void pool_mlp_kernel(const float* __restrict__ h3, const int* __restrict__ batch,
                                const float* __restrict__ fc1_w, const float* __restrict__ fc1_b,
                                const float* __restrict__ out_w, const float* __restrict__ out_b,
                                float* __restrict__ out) {
  const int b = blockIdx.x;
  const int tid = threadIdx.x;
  __shared__ float g[45];
  __shared__ float go[90];
  __shared__ int rng[2];
  if (tid < 2) {
    int target = b + tid;
    int lo = 0, hi = NN;
    while (lo < hi) { int mid = (lo + hi) >> 1; if (batch[mid] < target) lo = mid + 1; else hi = mid; }
    rng[tid] = lo;
  }
  __syncthreads();
  const int s = rng[0], e = rng[1];
  if (tid < 45) {
    float acc = 0.f;
    for (int n = s; n < e; n++) acc += h3[n * 45 + tid];
    g[tid] = acc;
  }
  __syncthreads();
  if (tid < 90) {
    float acc = fc1_b[tid];
#pragma unroll 5
    for (int i = 0; i < 45; i++) acc = fmaf(g[i], fc1_w[i * 90 + tid], acc);
    go[tid] = fmaxf(acc, 0.f) * out_w[tid];
  }
  __syncthreads();
  if (tid == 0) {
    float acc = out_b[0];
    for (int i = 0; i < 90; i++) acc += go[i];
    out[b] = acc;
  }
}

extern "C" void kernel_launch(void* const* d_in, const int* in_sizes, int n_in,
                              void* d_out, int out_size, void* d_ws, size_t ws_size,
                              hipStream_t stream) {
  const float* x       = (const float*)d_in[0];
  const float* pos     = (const float*)d_in[1];
  const float* ea      = (const float*)d_in[2];
  const int*   eidx    = (const int*)d_in[3];
  const int*   batch   = (const int*)d_in[4];
  const float* c1_w1   = (const float*)d_in[5];
  const float* c1_b1   = (const float*)d_in[6];
  const float* c1_w2   = (const float*)d_in[7];
  const float* c1_b2   = (const float*)d_in[8];
  const float* c1_root = (const float*)d_in[9];
  const float* c1_bias = (const float*)d_in[10];
  const float* c2_w1   = (const float*)d_in[11];
  const float* c2_b1   = (const float*)d_in[12];
  const float* c2_w2   = (const float*)d_in[13];
  const float* c2_b2   = (const float*)d_in[14];
  const float* c2_root = (const float*)d_in[15];
  const float* c2_bias = (const float*)d_in[16];
  const float* c3_w1   = (const float*)d_in[17];
  const float* c3_b1   = (const float*)d_in[18];
  const float* c3_w2   = (const float*)d_in[19];
  const float* c3_b2   = (const float*)d_in[20];
  const float* c3_root = (const float*)d_in[21];
  const float* c3_bias = (const float*)d_in[22];
  const float* fc1_w   = (const float*)d_in[23];
  const float* fc1_b   = (const float*)d_in[24];
  const float* out_w   = (const float*)d_in[25];
  const float* out_b   = (const float*)d_in[26];
  const int* src = eidx;
  const int* dst = eidx + NE;

  // workspace carve
  float* ws  = (float*)d_ws;
  float* h0  = ws;                       // NN*16
  float* h1  = h0 + NN * 16;             // NN*90
  float* h2  = h1 + NN * 90;             // NN*90
  float* h3  = h2 + NN * 90;             // NN*45
  float* agg = h3 + NN * 45;             // NN*90
  unsigned short* he_bf = (unsigned short*)(agg + NN * 90);   // NE*96
  unsigned short* wp1 = he_bf + (size_t)NE * 96;              // 16*6*3*512
  unsigned short* wp2 = wp1 + (size_t)16 * 6 * 3 * 512;       // 90*6*3*512
  unsigned short* wp3 = wp2 + (size_t)90 * 6 * 3 * 512;       // 90*3*3*512

  // 1: concat + agg-zero + all W' prep + conv1 edge MLP (one launch)
  prep_kernel<<<NB_CONCAT + NB_WPREP + NB_EDGE, 256, 0, stream>>>(
      x, pos, h0, agg, c1_w2, c1_b2, c2_w2, c2_b2, c3_w2, c3_b2,
      wp1, wp2, wp3, ea, c1_w1, c1_b1, he_bf);

  // 2-3: conv1 msg (256 edges/block, 8 waves) + [node1 ∪ edge2]
  msg_mfma<16, 90, 6, 2, 4, 256, 512><<<NE / 256, 512, 0, stream>>>(he_bf, h0, src, dst, wp1, agg);
  node_edge<16, 90><<<NB_EDGE, 256, 0, stream>>>(agg, h0, c1_root, c1_bias, h1,
                                                 ea, c2_w1, c2_b1, he_bf);

  // 4-5: conv2 msg (128 edges/block, 4 waves — proven R7 config) + [node2 ∪ edge3]
  msg_mfma<90, 90, 6, 2, 4, 128, 256><<<NE / 128, 256, 0, stream>>>(he_bf, h1, src, dst, wp2, agg);
  node_edge<90, 90><<<NB_EDGE, 256, 0, stream>>>(agg, h1, c2_root, c2_bias, h2,
                                                 ea, c3_w1, c3_b1, he_bf);

  // 6-7: conv3 msg (256 edges/block, 4 waves) + node3
  msg_mfma<90, 45, 3, 1, 4, 256, 256><<<NE / 256, 256, 0, stream>>>(he_bf, h2, src, dst, wp3, agg);
  node_kernel<90, 45><<<(NN * 45 + 255) / 256, 256, 0, stream>>>(agg, h2, c3_root, c3_bias, h3);

  // 8: pool + MLP head
  pool_mlp_kernel<<<NG, 128, 0, stream>>>(h3, batch, fc1_w, fc1_b, out_w, out_b, (float*)d_out);
}

// Round 13
// 485.488 us; speedup vs baseline: 1.3089x; 1.0197x over previous
//
#include <hip/hip_runtime.h>

#define NN 16000   // nodes
#define NE 64000   // edges
#define HD 90      // hidden
#define NG 512     // graphs

typedef float f32x4 __attribute__((ext_vector_type(4)));
typedef short s16x8 __attribute__((ext_vector_type(8)));

// round-half-up f32 -> bf16
__device__ __forceinline__ unsigned short rhu1(float f) {
  return (unsigned short)((__builtin_bit_cast(unsigned int, f) + 0x8000u) >> 16);
}
// pack two f32 -> bf16x2 (lo in low half), RHU rounding
__device__ __forceinline__ unsigned int rhu_pack(float lo, float hi) {
  unsigned int ul = __builtin_bit_cast(unsigned int, lo) + 0x8000u;
  unsigned int uh = __builtin_bit_cast(unsigned int, hi) + 0x8000u;
  return __builtin_amdgcn_perm(uh, ul, 0x07060302u);
}
__device__ __forceinline__ float bfhi(unsigned int u) {
  return __builtin_bit_cast(float, u & 0xFFFF0000u);
}
__device__ __forceinline__ float bflo(unsigned int u) {
  return __builtin_bit_cast(float, u << 16);
}

// shared edge-MLP body (R7-proven 1-wide form; bit-identical everywhere).
// R8 lesson: do NOT fuse into msg_mfma (scratch spill). R10 lesson: the
// 4-wide rewrite regressed — keep this exact form.
__device__ __forceinline__ void edge_mlp_one(int idx, const float* __restrict__ ea,
                                             const float* __restrict__ w1,
                                             const float* __restrict__ b1,
                                             unsigned short* __restrict__ he) {
  int e = idx / 96, k = idx - e * 96;
  unsigned short v;
  if (k < 90) {
    const float* a = ea + e * 8;
    float acc = b1[k];
#pragma unroll
    for (int j = 0; j < 8; j++) acc = fmaf(a[j], w1[j * HD + k], acc);
    v = rhu1(fmaxf(acc, 0.f));
  } else {
    v = (k == 90) ? (unsigned short)0x3F80 : (unsigned short)0;  // bf16(1.0) / 0
  }
  he[idx] = v;
}

// R12 mega-prep (1 launch, block-range dispatch; all parts independent):
//   blocks [0,5625):        h0 = concat(x,pos) + agg zero
//   blocks [5625,6213):     W' prep for all three convs (R11 wprep_all body)
//   blocks [6213,30213):    edge MLP for conv1 -> he
#define NB_CONCAT 5625      // NN*90/256
#define NB_WPREP  588       // 48 + 270 + 270
#define NB_EDGE   24000     // NE*96/256
__global__ void prep_kernel(const float* __restrict__ x, const float* __restrict__ pos,
                            float* __restrict__ h0, float* __restrict__ agg,
                            const float* __restrict__ w2a, const float* __restrict__ b2a,
                            const float* __restrict__ w2b, const float* __restrict__ b2b,
                            const float* __restrict__ w2c, const float* __restrict__ b2c,
                            unsigned short* __restrict__ wo1, unsigned short* __restrict__ wo2,
                            unsigned short* __restrict__ wo3,
                            const float* __restrict__ ea, const float* __restrict__ w1,
                            const float* __restrict__ b1, unsigned short* __restrict__ he) {
  const int b = blockIdx.x;
  const int tid = threadIdx.x;
  __shared__ float t_s[32 * 100];
  if (b < NB_CONCAT) {
    int idx = b * 256 + tid;                    // < NN*90
    agg[idx] = 0.f;
    if (idx < NN * 16) {
      int n = idx >> 4, c = idx & 15;
      h0[idx] = (c < 13) ? x[n * 13 + c] : pos[n * 3 + (c - 13)];
    }
    return;
  }
  if (b >= NB_CONCAT + NB_WPREP) {
    edge_mlp_one((b - NB_CONCAT - NB_WPREP) * 256 + tid, ea, w1, b1, he);
    return;
  }
  // --- wprep (R11 wprep_all body) ---
  const int wb = b - NB_CONCAT;
  const float* w2; const float* b2; unsigned short* wout;
  int OC, NTT, inc, ib;
  if (wb < 48)       { w2 = w2a; b2 = b2a; wout = wo1; OC = 90; NTT = 6; inc = 16 * 90; ib = wb; }
  else if (wb < 318) { w2 = w2b; b2 = b2b; wout = wo2; OC = 90; NTT = 6; inc = 90 * 90; ib = wb - 48; }
  else               { w2 = w2c; b2 = b2c; wout = wo3; OC = 45; NTT = 3; inc = 90 * 45; ib = wb - 318; }
  const int i = ib / 3, c = ib - 3 * i;
  for (int idx = tid; idx < 32 * 96; idx += 256) {
    int kk = idx / 96, o = idx - kk * 96;
    int hk = c * 32 + kk;
    float v = 0.f;
    if (o < OC) {
      if (hk < 90) v = w2[hk * inc + i * OC + o];           // coalesced along o
      else if (hk == 90) v = b2[i * OC + o];
    }
    t_s[kk * 100 + o] = v;
  }
  __syncthreads();
  unsigned int* wo = (unsigned int*)(wout + (size_t)i * NTT * 3 * 512) + c * 256;
  for (int idx = tid; idx < NTT * 256; idx += 256) {
    int t = idx >> 8, r = idx & 255;
    int lane = r >> 2, u = r & 3;
    int kk = (lane >> 4) * 8 + 2 * u;
    int o = t * 16 + (lane & 15);
    wo[(size_t)t * 3 * 256 + lane * 4 + u] = rhu_pack(t_s[kk * 100 + o], t_s[(kk + 1) * 100 + o]);
  }
}

// Fused message GEMM + scatter, LDS-staged W' (R3) + MT m-tiles/wave (R4)
// + distinct ping/pong LDS objects so AA lets stage-issue float past the
// ds_reads (R5; the only vmcnt(0) is the pre-barrier drain, covered by the
// MFMA phase). R6 counted-vmcnt ring: −1.75x (broadcast W' stream thrashes
// L2 + agg lines). R8 edge-MLP fusion: −1.4x (scratch spill). R9 conv2
// EPB=256: −8% (84KB LDS -> 1 block/CU -> nothing covers the per-iter
// barrier drain). RULE: keep >=2 blocks/CU when ILIM is large (drain
// coverage); 1-block/CU slab-sharing pays only in the staging-dominated
// regime (conv1, ILIM=16).
// R13: conv3 retiled EPB 256->128 with MT 4->2 (still 4 waves/block):
// grid 250->500 = 2 blocks/CU for drain coverage (R9 mechanism applied in
// the winning direction); MT=2's doubled LDS-reads-per-MFMA measured
// neutral at equal occupancy (R3->R4: 135.8 vs 136.6 on conv2).
template <int ILIM, int OC, int NTT, int NWG, int MT, int EPB, int BLK>
__global__ __launch_bounds__(BLK, 2)
void msg_mfma(const unsigned short* __restrict__ he,
              const float* __restrict__ nin,
              const int* __restrict__ src, const int* __restrict__ dst,
              const unsigned short* __restrict__ wp,
              float* __restrict__ agg) {
  constexpr int WMG = EPB / 32;          // 32-edge z-groups per block
  constexpr int TPE = BLK / EPB;
  constexpr int NWAVES = BLK / 64;       // = (EPB/(16*MT)) * NWG
  constexpr int NF = NTT * 3;            // 1KB fragments per i (whole W'[i])
  constexpr int MG = MT / 2;             // z-groups per wave
  __shared__ unsigned short zb[ILIM * WMG * 32];   // [i][grp][q][8] bf16, quad-permuted
  __shared__ unsigned short wbA[NF * 512];         // W' ping buffer (distinct object!)
  __shared__ unsigned short wbB[NF * 512];         // W' pong buffer (distinct object!)
  __shared__ int dst_s[EPB];
  const int tid = threadIdx.x;
  const int e0 = blockIdx.x * EPB;
  const int wid = tid >> 6, l = tid & 63, ln = tid & 15, q = (tid & 63) >> 4;
  const int wn = wid % NWG, wm = wid / NWG;
  const int eb = wm * MT * 16;
  const int wn3 = wn * 3;

  // stage W' slab (NF x 1KB fragments) -> the given LDS buffer, frags
  // distributed over waves. LDS dest is wave-uniform base (+lane*16);
  // global src is per-lane.
  const unsigned short* wl = wp + l * 8;
  auto stage = [&](const unsigned short* wb, unsigned short* lb) {
#pragma unroll
    for (int t = 0; t < (NF + NWAVES - 1) / NWAVES; t++) {
      const int s = wid + t * NWAVES;
      if (s < NF) {
        __builtin_amdgcn_global_load_lds(
            (const __attribute__((address_space(1))) unsigned int*)(wb + (size_t)s * 512),
            (__attribute__((address_space(3))) unsigned int*)(lb + s * 512),
            16, 0, 0);
      }
    }
  };

  // one i-step: z decode + 9 b128 W' reads from lb + 9*MT MFMA + acc FMA
  f32x4 acc[MT][3];
  s16x8 af[MT][3];
  auto compute = [&](int i, const unsigned short* lb) {
    f32x4 zv[MT];
#pragma unroll
    for (int g = 0; g < MG; g++) {
      const uint4 zu = *(const uint4*)&zb[(i * WMG + wm * MG + g) * 32 + q * 8];
      zv[2 * g][0] = bflo(zu.x); zv[2 * g][1] = bfhi(zu.x);
      zv[2 * g][2] = bflo(zu.y); zv[2 * g][3] = bfhi(zu.y);
      zv[2 * g + 1][0] = bflo(zu.z); zv[2 * g + 1][1] = bfhi(zu.z);
      zv[2 * g + 1][2] = bflo(zu.w); zv[2 * g + 1][3] = bfhi(zu.w);
    }
    uint4 ba[9];
#pragma unroll
    for (int ntl = 0; ntl < 3; ntl++)
#pragma unroll
      for (int c = 0; c < 3; c++)
        ba[ntl * 3 + c] = *(const uint4*)(lb + ((wn3 + ntl) * 3 + c) * 512 + l * 8);
#pragma unroll
    for (int ntl = 0; ntl < 3; ntl++) {
#pragma unroll
      for (int mt = 0; mt < MT; mt++) {
        f32x4 t = __builtin_amdgcn_mfma_f32_16x16x32_bf16(af[mt][0], __builtin_bit_cast(s16x8, ba[ntl * 3 + 0]), (f32x4)0.f, 0, 0, 0);
        t = __builtin_amdgcn_mfma_f32_16x16x32_bf16(af[mt][1], __builtin_bit_cast(s16x8, ba[ntl * 3 + 1]), t, 0, 0, 0);
        t = __builtin_amdgcn_mfma_f32_16x16x32_bf16(af[mt][2], __builtin_bit_cast(s16x8, ba[ntl * 3 + 2]), t, 0, 0, 0);
        acc[mt][ntl] += zv[mt] * t;
      }
    }
  };

  stage(wl, wbA);   // prefetch W'[0] while we stage z / load af

  if (tid < EPB) dst_s[tid] = dst[e0 + tid];

  // stage z (bf16) into quad-permuted layout:
  //   slot(e,i) = (i*WMG + (e>>5))*32 + ((e&15)>>2)*8 + ((e>>4)&1)*4 + (e&3)
  {
    const int e = tid % EPB, jj = tid / EPB;
    const int base = (e >> 5) * 32 + (((e & 15) >> 2) << 3) + (((e >> 4) & 1) << 2) + (e & 3);
    const float* zr = nin + (size_t)src[e0 + e] * ILIM;
    for (int p = jj; p < ILIM / 2; p += TPE) {
      const float2 v = *(const float2*)(zr + 2 * p);
      zb[(2 * p) * (WMG * 32) + base] = rhu1(v.x);
      zb[(2 * p + 1) * (WMG * 32) + base] = rhu1(v.y);
    }
  }

  // A-fragments: raw bf16 he, register-resident for the whole kernel
#pragma unroll
  for (int mt = 0; mt < MT; mt++) {
    const unsigned short* hr = he + (size_t)(e0 + eb + mt * 16 + ln) * 96 + q * 8;
#pragma unroll
    for (int c = 0; c < 3; c++) af[mt][c] = *(const s16x8*)(hr + c * 32);
  }

#pragma unroll
  for (int mt = 0; mt < MT; mt++)
#pragma unroll
    for (int nt = 0; nt < 3; nt++) acc[mt][nt] = (f32x4)0.f;

  __syncthreads();   // zb/dst_s ready AND wbA staged (vmcnt drained)

  const unsigned short* wnext = wl + (size_t)NF * 512;   // W'[1] base (per-lane)

#pragma clang loop unroll(disable)
  for (int i = 0; i < ILIM; i += 2) {
    // even half: stage i+1 -> wbB (distinct object: no false dep on wbA
    // reads), compute i from wbA, barrier (drains own stage loads).
    stage(wnext, wbB);
    wnext += (size_t)NF * 512;
    compute(i, wbA);
    __syncthreads();
    // odd half: stage i+2 -> wbA (if it exists), compute i+1 from wbB.
    if (i + 2 < ILIM) {
      stage(wnext, wbA);
      wnext += (size_t)NF * 512;
    }
    compute(i + 1, wbB);
    if (i + 2 < ILIM) __syncthreads();
  }

  // epilogue: D[row=q*4+r][col=ln] -> atomicAdd agg[dst]
#pragma unroll
  for (int mt = 0; mt < MT; mt++) {
#pragma unroll
    for (int ntl = 0; ntl < 3; ntl++) {
      int o = wn * 48 + ntl * 16 + ln;
      if (o < OC) {
#pragma unroll
        for (int r = 0; r < 4; r++) {
          int el = eb + mt * 16 + q * 4 + r;
          atomicAdd(agg + (size_t)dst_s[el] * OC + o, acc[mt][ntl][r]);
        }
      }
    }
  }
}

// node body: out[n][o] = relu(agg[n][o] + sum_i nin[n][i]*root[i][o] + bias[o])
// (fp32 exact). Also RE-ZEROES agg[idx] after reading, through the SAME
// pointer (load-before-store, order-guaranteed) — replaces memset launches.
template <int IN_C, int OC>
__device__ __forceinline__ void node_one(int idx, float* __restrict__ agg,
                                         const float* __restrict__ nin,
                                         const float* __restrict__ root,
                                         const float* __restrict__ bias,
                                         float* __restrict__ out) {
  int n = idx / OC, o = idx - n * OC;
  float acc = agg[idx] + bias[o];
  agg[idx] = 0.f;
  const float* inp = nin + (size_t)n * IN_C;
#pragma unroll 6
  for (int i = 0; i < IN_C; i++) acc = fmaf(inp[i], root[i * OC + o], acc);
  out[idx] = fmaxf(acc, 0.f);
}

// R12: node(conv k) + edge-MLP(conv k+1) merged — independent work on
// disjoint buffers (edge depends only on ea; runs after msg k consumed the
// previous he). Grid = NE*96/256 = 24000 blocks; node active in the first
// NN*OC/256 blocks' range.
template <int IN_C, int OC>
__global__ void node_edge(float* __restrict__ agg, const float* __restrict__ nin,
                          const float* __restrict__ root, const float* __restrict__ bias,
                          float* __restrict__ out,
                          const float* __restrict__ ea, const float* __restrict__ w1,
                          const float* __restrict__ b1, unsigned short* __restrict__ he) {
  int idx = blockIdx.x * 256 + threadIdx.x;    // < NE*96 exactly
  edge_mlp_one(idx, ea, w1, b1, he);
  if (idx < NN * OC) node_one<IN_C, OC>(idx, agg, nin, root, bias, out);
}

// plain node (conv3 — no following edge MLP)
template <int IN_C, int OC>
__global__ void node_kernel(float* __restrict__ agg, const float* __restrict__ nin,
                            const float* __restrict__ root, const float* __restrict__ bias,
                            float* __restrict__ out) {
  int idx = blockIdx.x * 256 + threadIdx.x;
  if (idx >= NN * OC) return;
  node_one<IN_C, OC>(idx, agg, nin, root, bias, out);
}

// per-graph: pool (batch sorted -> binary search) + fc1 + out
__global__ void pool_mlp_kernel(const float* __restrict__ h3, const int* __restrict__ batch,
                                const float* __restrict__ fc1_w, const float* __restrict__ fc1_b,
                                const float* __restrict__ out_w, const float* __restrict__ out_b,
                                float* __restrict__ out) {
  const int b = blockIdx.x;
  const int tid = threadIdx.x;
  __shared__ float g[45];
  __shared__ float go[90];
  __shared__ int rng[2];
  if (tid < 2) {
    int target = b + tid;
    int lo = 0, hi = NN;
    while (lo < hi) { int mid = (lo + hi) >> 1; if (batch[mid] < target) lo = mid + 1; else hi = mid; }
    rng[tid] = lo;
  }
  __syncthreads();
  const int s = rng[0], e = rng[1];
  if (tid < 45) {
    float acc = 0.f;
    for (int n = s; n < e; n++) acc += h3[n * 45 + tid];
    g[tid] = acc;
  }
  __syncthreads();
  if (tid < 90) {
    float acc = fc1_b[tid];
#pragma unroll 5
    for (int i = 0; i < 45; i++) acc = fmaf(g[i], fc1_w[i * 90 + tid], acc);
    go[tid] = fmaxf(acc, 0.f) * out_w[tid];
  }
  __syncthreads();
  if (tid == 0) {
    float acc = out_b[0];
    for (int i = 0; i < 90; i++) acc += go[i];
    out[b] = acc;
  }
}

extern "C" void kernel_launch(void* const* d_in, const int* in_sizes, int n_in,
                              void* d_out, int out_size, void* d_ws, size_t ws_size,
                              hipStream_t stream) {
  const float* x       = (const float*)d_in[0];
  const float* pos     = (const float*)d_in[1];
  const float* ea      = (const float*)d_in[2];
  const int*   eidx    = (const int*)d_in[3];
  const int*   batch   = (const int*)d_in[4];
  const float* c1_w1   = (const float*)d_in[5];
  const float* c1_b1   = (const float*)d_in[6];
  const float* c1_w2   = (const float*)d_in[7];
  const float* c1_b2   = (const float*)d_in[8];
  const float* c1_root = (const float*)d_in[9];
  const float* c1_bias = (const float*)d_in[10];
  const float* c2_w1   = (const float*)d_in[11];
  const float* c2_b1   = (const float*)d_in[12];
  const float* c2_w2   = (const float*)d_in[13];
  const float* c2_b2   = (const float*)d_in[14];
  const float* c2_root = (const float*)d_in[15];
  const float* c2_bias = (const float*)d_in[16];
  const float* c3_w1   = (const float*)d_in[17];
  const float* c3_b1   = (const float*)d_in[18];
  const float* c3_w2   = (const float*)d_in[19];
  const float* c3_b2   = (const float*)d_in[20];
  const float* c3_root = (const float*)d_in[21];
  const float* c3_bias = (const float*)d_in[22];
  const float* fc1_w   = (const float*)d_in[23];
  const float* fc1_b   = (const float*)d_in[24];
  const float* out_w   = (const float*)d_in[25];
  const float* out_b   = (const float*)d_in[26];
  const int* src = eidx;
  const int* dst = eidx + NE;

  // workspace carve
  float* ws  = (float*)d_ws;
  float* h0  = ws;                       // NN*16
  float* h1  = h0 + NN * 16;             // NN*90
  float* h2  = h1 + NN * 90;             // NN*90
  float* h3  = h2 + NN * 90;             // NN*45
  float* agg = h3 + NN * 45;             // NN*90
  unsigned short* he_bf = (unsigned short*)(agg + NN * 90);   // NE*96
  unsigned short* wp1 = he_bf + (size_t)NE * 96;              // 16*6*3*512
  unsigned short* wp2 = wp1 + (size_t)16 * 6 * 3 * 512;       // 90*6*3*512
  unsigned short* wp3 = wp2 + (size_t)90 * 6 * 3 * 512;       // 90*3*3*512

  // 1: concat + agg-zero + all W' prep + conv1 edge MLP (one launch)
  prep_kernel<<<NB_CONCAT + NB_WPREP + NB_EDGE, 256, 0, stream>>>(
      x, pos, h0, agg, c1_w2, c1_b2, c2_w2, c2_b2, c3_w2, c3_b2,
      wp1, wp2, wp3, ea, c1_w1, c1_b1, he_bf);

  // 2-3: conv1 msg (256 edges/block, 8 waves — staging-dominated, slab-shared) + [node1 ∪ edge2]
  msg_mfma<16, 90, 6, 2, 4, 256, 512><<<NE / 256, 512, 0, stream>>>(he_bf, h0, src, dst, wp1, agg);
  node_edge<16, 90><<<NB_EDGE, 256, 0, stream>>>(agg, h0, c1_root, c1_bias, h1,
                                                 ea, c2_w1, c2_b1, he_bf);

  // 4-5: conv2 msg (128 edges/block, 4 waves, 2 blocks/CU — proven R7 config) + [node2 ∪ edge3]
  msg_mfma<90, 90, 6, 2, 4, 128, 256><<<NE / 128, 256, 0, stream>>>(he_bf, h1, src, dst, wp2, agg);
  node_edge<90, 90><<<NB_EDGE, 256, 0, stream>>>(agg, h1, c2_root, c2_bias, h2,
                                                 ea, c3_w1, c3_b1, he_bf);

  // 6-7: conv3 msg — R13 retile: EPB=128, MT=2, 4 waves, 500 blocks = 2 blocks/CU
  msg_mfma<90, 45, 3, 1, 2, 128, 256><<<NE / 128, 256, 0, stream>>>(he_bf, h2, src, dst, wp3, agg);
  node_kernel<90, 45><<<(NN * 45 + 255) / 256, 256, 0, stream>>>(agg, h2, c3_root, c3_bias, h3);

  // 8: pool + MLP head
  pool_mlp_kernel<<<NG, 128, 0, stream>>>(h3, batch, fc1_w, fc1_b, out_w, out_b, (float*)d_out);
}